// Round 3
// baseline (76261.682 us; speedup 1.0000x reference)
//
#include <hip/hip_runtime.h>

// LSTMGapFiller R2: decoder -> MFMA bf16 hi/lo split-3 (K-tripled GEMMs,
// fp32-class accuracy), gates fused in epilogue. ctx kernels unchanged (R1).

#define L_SEQ 100
#define BATCH 1024
#define HCTX 256
#define HG 512
#define TDEC 256

typedef __attribute__((ext_vector_type(8))) short short8;
typedef __attribute__((ext_vector_type(4))) float f32x4;

__device__ __forceinline__ float sigf(float x){ return 1.0f/(1.0f+expf(-x)); }
__device__ __forceinline__ unsigned short f2bf(float f){
  unsigned u = __float_as_uint(f);
  unsigned r = (u + 0x7FFFu + ((u>>16)&1u)) >> 16;   // RNE
  return (unsigned short)r;
}
__device__ __forceinline__ float bf2f(unsigned short s){
  return __uint_as_float(((unsigned)s)<<16);
}

// src[J][K] -> dst[K][J]
__global__ void transpose_k(const float* __restrict__ src, float* __restrict__ dst,
                            int J, int K){
  int idx = blockIdx.x*blockDim.x + threadIdx.x;
  if (idx < J*K){
    int j = idx / K, k = idx % K;
    dst[k*J + j] = src[idx];
  }
}

// embedding projections + decoder bias pack:
// ectx0[d][v][j] = ctx0_b[d][j] + emb[v].ctx0_Wih[d][j]          (j<1024, gate-major)
// egen0p[v][u*4+g] = gen0_b[g*512+u] + emb[v].gen0_Wih[g*512+u]  (unit-interleaved)
// b1p[u*4+g] = gen1_b[g*512+u]
__global__ void embprep(const float* __restrict__ emb,
                        const float* __restrict__ c0Wih, const float* __restrict__ c0b,
                        const float* __restrict__ g0Wih, const float* __restrict__ g0b,
                        const float* __restrict__ g1b,
                        float* __restrict__ ectx0, float* __restrict__ egen0p,
                        float* __restrict__ b1p){
  int idx = blockIdx.x*blockDim.x + threadIdx.x;
  if (idx < 2*5*1024){
    int d = idx / 5120;
    int v = (idx / 1024) % 5;
    int j = idx % 1024;
    const float* w = c0Wih + ((size_t)d*1024 + j)*64;
    const float* e = emb + v*64;
    float s = c0b[d*1024 + j];
    #pragma unroll
    for (int k=0;k<64;k++) s += e[k]*w[k];
    ectx0[idx] = s;
  } else if (idx < 2*5*1024 + 5*2048){
    int i2 = idx - 10240;
    int v = i2 / 2048;
    int n = i2 % 2048;
    int u = n >> 2, g = n & 3;
    int r = g*512 + u;
    const float* w = g0Wih + (size_t)r*64;
    const float* e = emb + v*64;
    float s = g0b[r];
    #pragma unroll
    for (int k=0;k<64;k++) s += e[k]*w[k];
    egen0p[i2] = s;
  } else if (idx < 2*5*1024 + 5*2048 + 2048){
    int n = idx - 10240 - 10240;
    int u = n >> 2, g = n & 3;
    b1p[n] = g1b[g*512 + u];
  }
}

// Pack B fragments for the decoder GEMMs (fragment-linear, unit-interleaved cols).
// Element: Bp[((kt*128+nt)*64+lane)*8+j] = part(W[row][k]) where
//   n = nt*16 + (lane&15), u=n>>2, g=n&3, row = g*512+u,
//   k = (kt&15)*32 + (lane>>4)*8 + j, seg s = kt>>4.
// mode 0 (gen0, KT=48): src=Whh, part = (s==1)?lo:hi          A pairs [hi|hi|lo]
// mode 1 (gen1, KT=96): src = (s&1)?Whh:Wih, part=(s==2||s==3)?lo:hi
//   A pairs [x_hi|h_hi|x_hi|h_hi|x_lo|h_lo]
__global__ void pack_b(const float* __restrict__ Wih, const float* __restrict__ Whh,
                       short* __restrict__ Bp, int KT, int mode){
  int idx = blockIdx.x*blockDim.x + threadIdx.x;
  if (idx >= KT*128*64) return;
  int lane = idx & 63;
  int nt   = (idx >> 6) & 127;
  int kt   = idx >> 13;
  int quad = lane >> 4, l15 = lane & 15;
  int n = nt*16 + l15;
  int u = n >> 2, g = n & 3;
  int row = g*512 + u;
  int kb = (kt & 15)*32 + quad*8;
  int s = kt >> 4;
  const float* src; int lo;
  if (mode == 0){ src = Whh; lo = (s==1); }
  else          { src = (s&1) ? Whh : Wih; lo = (s==2 || s==3); }
  short* op = Bp + (size_t)idx*8;
  #pragma unroll
  for (int j=0;j<8;j++){
    float v = src[(size_t)row*512 + kb + j];
    unsigned short hb = f2bf(v);
    op[j] = lo ? (short)f2bf(v - bf2f(hb)) : (short)hb;
  }
}

// ---------------- ctx kernels (unchanged from R1) ----------------
__global__ void ctx_l0(const int* __restrict__ toks,
                       const float* __restrict__ ectx0,
                       const float* __restrict__ whhT,
                       float* __restrict__ y0){
  const int dir = blockIdx.y;
  const int e0 = blockIdx.x * 8;
  const int u = threadIdx.x & 255;
  const int eh = threadIdx.x >> 8;
  __shared__ float hs[8][256];
  __shared__ float cs[8][256];
  #pragma unroll
  for (int j=0;j<4;j++){ hs[eh*4+j][u]=0.f; cs[eh*4+j][u]=0.f; }
  __syncthreads();
  const float* wbase = whhT + (size_t)dir*256*1024;
  for (int s=0;s<L_SEQ;s++){
    const int t = dir ? (L_SEQ-1-s) : s;
    float acc[4][4];
    #pragma unroll
    for (int j=0;j<4;j++){
      int e = eh*4+j;
      int tk = toks[(e0+e)*L_SEQ + t];
      const float* ep = ectx0 + ((size_t)dir*5 + tk)*1024 + u;
      acc[j][0]=ep[0]; acc[j][1]=ep[256]; acc[j][2]=ep[512]; acc[j][3]=ep[768];
    }
    for (int k=0;k<256;k++){
      const float* w = wbase + k*1024 + u;
      float w0=w[0], w1=w[256], w2=w[512], w3=w[768];
      #pragma unroll
      for (int j=0;j<4;j++){
        float hv = hs[eh*4+j][k];
        acc[j][0]+=hv*w0; acc[j][1]+=hv*w1; acc[j][2]+=hv*w2; acc[j][3]+=hv*w3;
      }
    }
    __syncthreads();
    #pragma unroll
    for (int j=0;j<4;j++){
      int e = eh*4+j;
      float ig = sigf(acc[j][0]);
      float fg = sigf(acc[j][1]);
      float gg = tanhf(acc[j][2]);
      float og = sigf(acc[j][3]);
      float c = fg*cs[e][u] + ig*gg;
      float h = og*tanhf(c);
      cs[e][u]=c; hs[e][u]=h;
      y0[((size_t)t*BATCH + (e0+e))*512 + dir*256 + u] = h;
    }
    __syncthreads();
  }
}

__global__ void ctx_l1(const float* __restrict__ y0,
                       const float* __restrict__ wihT,
                       const float* __restrict__ whhT,
                       const float* __restrict__ bias,
                       float* __restrict__ finals, int t_store){
  const int dir = blockIdx.y;
  const int e0 = blockIdx.x * 8;
  const int u = threadIdx.x & 255;
  const int eh = threadIdx.x >> 8;
  __shared__ float hs[8][256];
  __shared__ float cs[8][256];
  __shared__ float xs[8][512];
  #pragma unroll
  for (int j=0;j<4;j++){ hs[eh*4+j][u]=0.f; cs[eh*4+j][u]=0.f; }
  __syncthreads();
  const float* wi = wihT + (size_t)dir*512*1024;
  const float* wh = whhT + (size_t)dir*256*1024;
  const float b0 = bias[dir*1024 + u];
  const float b1 = bias[dir*1024 + 256 + u];
  const float b2 = bias[dir*1024 + 512 + u];
  const float b3 = bias[dir*1024 + 768 + u];
  for (int s=0;s<L_SEQ;s++){
    const int t = dir ? (L_SEQ-1-s) : s;
    const float* xsrc = y0 + ((size_t)t*BATCH + e0)*512;
    for (int i=threadIdx.x;i<8*512;i+=512) ((float*)xs)[i] = xsrc[i];
    __syncthreads();
    float acc[4][4];
    #pragma unroll
    for (int j=0;j<4;j++){ acc[j][0]=b0; acc[j][1]=b1; acc[j][2]=b2; acc[j][3]=b3; }
    for (int k=0;k<512;k++){
      const float* w = wi + k*1024 + u;
      float w0=w[0], w1=w[256], w2=w[512], w3=w[768];
      #pragma unroll
      for (int j=0;j<4;j++){
        float xv = xs[eh*4+j][k];
        acc[j][0]+=xv*w0; acc[j][1]+=xv*w1; acc[j][2]+=xv*w2; acc[j][3]+=xv*w3;
      }
    }
    for (int k=0;k<256;k++){
      const float* w = wh + k*1024 + u;
      float w0=w[0], w1=w[256], w2=w[512], w3=w[768];
      #pragma unroll
      for (int j=0;j<4;j++){
        float hv = hs[eh*4+j][k];
        acc[j][0]+=hv*w0; acc[j][1]+=hv*w1; acc[j][2]+=hv*w2; acc[j][3]+=hv*w3;
      }
    }
    __syncthreads();
    #pragma unroll
    for (int j=0;j<4;j++){
      int e = eh*4+j;
      float ig = sigf(acc[j][0]);
      float fg = sigf(acc[j][1]);
      float gg = tanhf(acc[j][2]);
      float og = sigf(acc[j][3]);
      float c = fg*cs[e][u] + ig*gg;
      float h = og*tanhf(c);
      cs[e][u]=c; hs[e][u]=h;
      if (t == t_store) finals[(size_t)(e0+e)*512 + dir*256 + u] = h;
    }
    __syncthreads();
  }
}

// combined init: h0/h1 packs (bf16 hi|lo), h1 fp32, c=0, tok=0
__global__ void combine_init(const float* __restrict__ lf, const float* __restrict__ rf,
                             short* __restrict__ h0p, short* __restrict__ h1p,
                             float* __restrict__ h1f,
                             float* __restrict__ c0, float* __restrict__ c1,
                             int* __restrict__ tok){
  int i = blockIdx.x*blockDim.x + threadIdx.x;
  if (i < BATCH*HG){
    float v = 0.5f*(lf[i]+rf[i]);
    int e = i >> 9, u = i & 511;
    unsigned short hh = f2bf(v);
    unsigned short hl = f2bf(v - bf2f(hh));
    h0p[(size_t)e*1024 + u]       = (short)hh;
    h0p[(size_t)e*1024 + 512 + u] = (short)hl;
    h1p[(size_t)e*1024 + u]       = (short)hh;
    h1p[(size_t)e*1024 + 512 + u] = (short)hl;
    h1f[i] = v;
    c0[i] = 0.f; c1[i] = 0.f;
  }
  if (i < BATCH) tok[i] = 0;
}

// decoder layer 0 (MFMA): z = egen0p[tok] + h0_prev @ W0^T (K-tripled, KT=48)
// grid (16 M-tiles x 16 N-tiles), 256 thr. Tile 64M x 128N; wave w = rows w*16..+15.
__global__ void dec_l0(const int* __restrict__ tok,
                       const float* __restrict__ egen0p,
                       const short* __restrict__ Bp,
                       const short* __restrict__ hprev,
                       short* __restrict__ hnew,
                       float* __restrict__ cst){
  const int m0 = blockIdx.x * 64;
  const int nb0 = blockIdx.y * 8;
  const int u0 = blockIdx.y * 32;
  const int w = threadIdx.x >> 6;
  const int lane = threadIdx.x & 63;
  const int quad = lane >> 4, l15 = lane & 15;
  f32x4 acc[8];
  #pragma unroll
  for (int i=0;i<8;i++) acc[i] = (f32x4){0.f,0.f,0.f,0.f};
  const size_t arow = (size_t)(m0 + w*16 + l15)*1024;
  for (int kt=0; kt<48; ++kt){
    const int s = kt >> 4;
    const int off = (s==2) ? 512 : 0;
    const short8 a = *(const short8*)(hprev + arow + off + (kt&15)*32 + quad*8);
    const short* bb = Bp + (((size_t)kt*128 + nb0)*64 + lane)*8;
    #pragma unroll
    for (int nt=0; nt<8; ++nt){
      const short8 b = *(const short8*)(bb + (size_t)nt*512);
      acc[nt] = __builtin_amdgcn_mfma_f32_16x16x32_bf16(a, b, acc[nt], 0, 0, 0);
    }
  }
  __shared__ float zt[64][132];
  #pragma unroll
  for (int nt=0; nt<8; ++nt)
    #pragma unroll
    for (int r=0;r<4;r++)
      zt[w*16 + quad*4 + r][nt*16 + l15] = acc[nt][r];
  __syncthreads();
  for (int i=0;i<8;i++){
    int p = threadIdx.x + 256*i;
    int el = p >> 5, ul = p & 31;
    int e = m0 + el, u = u0 + ul;
    const float* eg = egen0p + (size_t)tok[e]*2048 + (size_t)(u0+ul)*4;
    float z0 = zt[el][ul*4+0] + eg[0];
    float z1 = zt[el][ul*4+1] + eg[1];
    float z2 = zt[el][ul*4+2] + eg[2];
    float z3 = zt[el][ul*4+3] + eg[3];
    float ig = sigf(z0), fg = sigf(z1), gg = tanhf(z2), og = sigf(z3);
    size_t ci = (size_t)e*512 + u;
    float c = fg*cst[ci] + ig*gg;
    float h = og*tanhf(c);
    cst[ci] = c;
    unsigned short hh = f2bf(h);
    unsigned short hl = f2bf(h - bf2f(hh));
    hnew[(size_t)e*1024 + u]       = (short)hh;
    hnew[(size_t)e*1024 + 512 + u] = (short)hl;
  }
}

// decoder layer 1 (MFMA): z = b1 + [h0_new; h1_prev] @ W1^T (K-tripled, KT=96)
__global__ void dec_l1(const short* __restrict__ h0new,
                       const short* __restrict__ h1prev,
                       const short* __restrict__ Bp,
                       const float* __restrict__ b1p,
                       short* __restrict__ h1new,
                       float* __restrict__ h1f,
                       float* __restrict__ cst){
  const int m0 = blockIdx.x * 64;
  const int nb0 = blockIdx.y * 8;
  const int u0 = blockIdx.y * 32;
  const int w = threadIdx.x >> 6;
  const int lane = threadIdx.x & 63;
  const int quad = lane >> 4, l15 = lane & 15;
  f32x4 acc[8];
  #pragma unroll
  for (int i=0;i<8;i++) acc[i] = (f32x4){0.f,0.f,0.f,0.f};
  const size_t arow = (size_t)(m0 + w*16 + l15)*1024;
  for (int kt=0; kt<96; ++kt){
    const int s = kt >> 4;
    const short* abuf = (s & 1) ? h1prev : h0new;
    const int off = (s >= 4) ? 512 : 0;
    const short8 a = *(const short8*)(abuf + arow + off + (kt&15)*32 + quad*8);
    const short* bb = Bp + (((size_t)kt*128 + nb0)*64 + lane)*8;
    #pragma unroll
    for (int nt=0; nt<8; ++nt){
      const short8 b = *(const short8*)(bb + (size_t)nt*512);
      acc[nt] = __builtin_amdgcn_mfma_f32_16x16x32_bf16(a, b, acc[nt], 0, 0, 0);
    }
  }
  __shared__ float zt[64][132];
  #pragma unroll
  for (int nt=0; nt<8; ++nt)
    #pragma unroll
    for (int r=0;r<4;r++)
      zt[w*16 + quad*4 + r][nt*16 + l15] = acc[nt][r];
  __syncthreads();
  for (int i=0;i<8;i++){
    int p = threadIdx.x + 256*i;
    int el = p >> 5, ul = p & 31;
    int e = m0 + el, u = u0 + ul;
    const float* bp = b1p + (size_t)(u0+ul)*4;
    float z0 = zt[el][ul*4+0] + bp[0];
    float z1 = zt[el][ul*4+1] + bp[1];
    float z2 = zt[el][ul*4+2] + bp[2];
    float z3 = zt[el][ul*4+3] + bp[3];
    float ig = sigf(z0), fg = sigf(z1), gg = tanhf(z2), og = sigf(z3);
    size_t ci = (size_t)e*512 + u;
    float c = fg*cst[ci] + ig*gg;
    float h = og*tanhf(c);
    cst[ci] = c;
    unsigned short hh = f2bf(h);
    unsigned short hl = f2bf(h - bf2f(hh));
    h1new[(size_t)e*1024 + u]       = (short)hh;
    h1new[(size_t)e*1024 + 512 + u] = (short)hl;
    h1f[ci] = h;
  }
}

// logits + argmax: one wave per batch elem
__global__ void dec_out(const float* __restrict__ h1,
                        const float* __restrict__ outW,
                        const float* __restrict__ outb,
                        float* __restrict__ out,
                        int* __restrict__ tok, int t){
  const int lane = threadIdx.x & 63;
  const int e = blockIdx.x*4 + (threadIdx.x >> 6);
  const float* h = h1 + (size_t)e*512;
  float s0=0,s1=0,s2=0,s3=0,s4=0;
  for (int k=lane;k<512;k+=64){
    float hv = h[k];
    s0 += hv*outW[k];
    s1 += hv*outW[512+k];
    s2 += hv*outW[1024+k];
    s3 += hv*outW[1536+k];
    s4 += hv*outW[2048+k];
  }
  #pragma unroll
  for (int off=32; off>0; off>>=1){
    s0 += __shfl_down(s0, off);
    s1 += __shfl_down(s1, off);
    s2 += __shfl_down(s2, off);
    s3 += __shfl_down(s3, off);
    s4 += __shfl_down(s4, off);
  }
  if (lane==0){
    float l[5] = { s0+outb[0], s1+outb[1], s2+outb[2], s3+outb[3], s4+outb[4] };
    float* op = out + ((size_t)e*TDEC + t)*5;
    float best = l[0]; int bi = 0;
    op[0] = l[0];
    #pragma unroll
    for (int v=1;v<5;v++){
      op[v] = l[v];
      if (l[v] > best){ best = l[v]; bi = v; }
    }
    tok[e] = bi;
  }
}

extern "C" void kernel_launch(void* const* d_in, const int* in_sizes, int n_in,
                              void* d_out, int out_size, void* d_ws, size_t ws_size,
                              hipStream_t stream){
  (void)in_sizes; (void)n_in; (void)out_size;
  const int*   leftc    = (const int*)d_in[0];
  const int*   rightc   = (const int*)d_in[1];
  const float* emb      = (const float*)d_in[3];
  const float* ctx0_Wih = (const float*)d_in[4];
  const float* ctx0_Whh = (const float*)d_in[5];
  const float* ctx0_b   = (const float*)d_in[6];
  const float* ctx1_Wih = (const float*)d_in[7];
  const float* ctx1_Whh = (const float*)d_in[8];
  const float* ctx1_b   = (const float*)d_in[9];
  const float* gen0_Wih = (const float*)d_in[10];
  const float* gen0_Whh = (const float*)d_in[11];
  const float* gen0_b   = (const float*)d_in[12];
  const float* gen1_Wih = (const float*)d_in[13];
  const float* gen1_Whh = (const float*)d_in[14];
  const float* gen1_b   = (const float*)d_in[15];
  const float* out_W    = (const float*)d_in[16];
  const float* out_b    = (const float*)d_in[17];
  float* out = (float*)d_out;

  char* p = (char*)d_ws;
  auto carveB = [&](size_t nbytes)->char*{
    char* r = p;
    p += ((nbytes + 255) & ~(size_t)255);
    return r;
  };
  float* c0WhhT = (float*)carveB((size_t)2*256*1024*4);
  float* c1WihT = (float*)carveB((size_t)2*512*1024*4);
  float* c1WhhT = (float*)carveB((size_t)2*256*1024*4);
  short* Bp0    = (short*)carveB((size_t)48*128*64*8*2);   // 6 MB
  short* Bp1    = (short*)carveB((size_t)96*128*64*8*2);   // 12 MB
  float* ectx0  = (float*)carveB(2*5*1024*4);
  float* egen0p = (float*)carveB(5*2048*4);
  float* b1p    = (float*)carveB(2048*4);
  float* leftF  = (float*)carveB((size_t)BATCH*HG*4);
  float* rightF = (float*)carveB((size_t)BATCH*HG*4);
  short* h0pA   = (short*)carveB((size_t)BATCH*1024*2);
  short* h0pB   = (short*)carveB((size_t)BATCH*1024*2);
  short* h1pA   = (short*)carveB((size_t)BATCH*1024*2);
  short* h1pB   = (short*)carveB((size_t)BATCH*1024*2);
  float* h1f32  = (float*)carveB((size_t)BATCH*HG*4);
  float* c0s    = (float*)carveB((size_t)BATCH*HG*4);
  float* c1s    = (float*)carveB((size_t)BATCH*HG*4);
  int*   tok    = (int*)carveB(BATCH*4);
  float* y0     = (float*)carveB((size_t)L_SEQ*BATCH*512*4);  // 210 MB, largest last
  if ((size_t)(p - (char*)d_ws) > ws_size) return;

  auto T = [&](const float* s, float* d, int J, int K){
    int n = J*K;
    transpose_k<<<(n+255)/256, 256, 0, stream>>>(s, d, J, K);
  };
  T(ctx0_Whh,          c0WhhT,          1024, 256);
  T(ctx0_Whh+1024*256, c0WhhT+256*1024, 1024, 256);
  T(ctx1_Wih,          c1WihT,          1024, 512);
  T(ctx1_Wih+1024*512, c1WihT+512*1024, 1024, 512);
  T(ctx1_Whh,          c1WhhT,          1024, 256);
  T(ctx1_Whh+1024*256, c1WhhT+256*1024, 1024, 256);
  embprep<<<(22528+255)/256, 256, 0, stream>>>(emb, ctx0_Wih, ctx0_b,
                                               gen0_Wih, gen0_b, gen1_b,
                                               ectx0, egen0p, b1p);
  pack_b<<<(48*128*64+255)/256, 256, 0, stream>>>(gen0_Whh, gen0_Whh, Bp0, 48, 0);
  pack_b<<<(96*128*64+255)/256, 256, 0, stream>>>(gen1_Wih, gen1_Whh, Bp1, 96, 1);

  ctx_l0<<<dim3(128,2), 512, 0, stream>>>(leftc, ectx0, c0WhhT, y0);
  ctx_l1<<<dim3(128,2), 512, 0, stream>>>(y0, c1WihT, c1WhhT, ctx1_b, leftF, L_SEQ-1);
  ctx_l0<<<dim3(128,2), 512, 0, stream>>>(rightc, ectx0, c0WhhT, y0);
  ctx_l1<<<dim3(128,2), 512, 0, stream>>>(y0, c1WihT, c1WhhT, ctx1_b, rightF, 0);

  combine_init<<<(BATCH*HG+255)/256, 256, 0, stream>>>(leftF, rightF,
                                                       h0pA, h1pA, h1f32,
                                                       c0s, c1s, tok);

  for (int t=0;t<TDEC;t++){
    short* h0in  = (t&1) ? h0pB : h0pA;
    short* h0out = (t&1) ? h0pA : h0pB;
    short* h1in  = (t&1) ? h1pB : h1pA;
    short* h1out = (t&1) ? h1pA : h1pB;
    dec_l0<<<dim3(16,16), 256, 0, stream>>>(tok, egen0p, Bp0, h0in, h0out, c0s);
    dec_l1<<<dim3(16,16), 256, 0, stream>>>(h0out, h1in, Bp1, b1p,
                                            h1out, h1f32, c1s);
    dec_out<<<256, 256, 0, stream>>>(h1f32, out_W, out_b, out, tok, t);
  }
}

// Round 5
// 72839.050 us; speedup vs baseline: 1.0470x; 1.0470x over previous
//
#include <hip/hip_runtime.h>

// LSTMGapFiller R4: R3 (full MFMA ctx+decoder, bf16 hi/lo split-3) with
// workspace aliasing to fit the cap: ctx-only buffers union'd with decoder
// packs (20 MiB), y0 sequence union'd with decoder state (200 MiB). Decoder
// pack_b launches moved after ctx. Total ~224 MiB (R3's 256.4 overflowed).

#define L_SEQ 100
#define BATCH 1024
#define HG 512
#define TDEC 256

typedef __attribute__((ext_vector_type(8))) short short8;
typedef __attribute__((ext_vector_type(4))) float f32x4;

__device__ __forceinline__ float sigf(float x){ return 1.0f/(1.0f+expf(-x)); }
__device__ __forceinline__ unsigned short f2bf(float f){
  unsigned u = __float_as_uint(f);
  unsigned r = (u + 0x7FFFu + ((u>>16)&1u)) >> 16;   // RNE
  return (unsigned short)r;
}
__device__ __forceinline__ float bf2f(unsigned short s){
  return __uint_as_float(((unsigned)s)<<16);
}

// embedding projections + bias packs (unit-interleaved for MFMA epilogues)
__global__ void embprep(const float* __restrict__ emb,
                        const float* __restrict__ c0Wih, const float* __restrict__ c0b,
                        const float* __restrict__ g0Wih, const float* __restrict__ g0b,
                        const float* __restrict__ g1b,  const float* __restrict__ c1b,
                        float* __restrict__ ectx0p, float* __restrict__ egen0p,
                        float* __restrict__ b1p, float* __restrict__ ctxb1p){
  int idx = blockIdx.x*blockDim.x + threadIdx.x;
  if (idx < 2*5*1024){
    int d = idx / 5120;
    int v = (idx / 1024) % 5;
    int n = idx % 1024;
    int u = n >> 2, g = n & 3;
    int row = g*256 + u;
    const float* w = c0Wih + ((size_t)d*1024 + row)*64;
    const float* e = emb + v*64;
    float s = c0b[d*1024 + row];
    #pragma unroll
    for (int k=0;k<64;k++) s += e[k]*w[k];
    ectx0p[idx] = s;
  } else if (idx < 10240 + 5*2048){
    int i2 = idx - 10240;
    int v = i2 / 2048;
    int n = i2 % 2048;
    int u = n >> 2, g = n & 3;
    int r = g*512 + u;
    const float* w = g0Wih + (size_t)r*64;
    const float* e = emb + v*64;
    float s = g0b[r];
    #pragma unroll
    for (int k=0;k<64;k++) s += e[k]*w[k];
    egen0p[i2] = s;
  } else if (idx < 10240 + 10240 + 2048){
    int n = idx - 20480;
    int u = n >> 2, g = n & 3;
    b1p[n] = g1b[g*512 + u];
  } else if (idx < 10240 + 10240 + 2048 + 2048){
    int i4 = idx - 22528;
    int d = i4 >> 10, n = i4 & 1023;
    int u = n >> 2, g = n & 3;
    ctxb1p[i4] = c1b[d*1024 + g*256 + u];
  }
}

// Decoder B-pack (verified R2). Bp[((kt*128+nt)*64+lane)*8+j].
__global__ void pack_b(const float* __restrict__ Wih, const float* __restrict__ Whh,
                       short* __restrict__ Bp, int KT, int mode){
  int idx = blockIdx.x*blockDim.x + threadIdx.x;
  if (idx >= KT*128*64) return;
  int lane = idx & 63;
  int nt   = (idx >> 6) & 127;
  int kt   = idx >> 13;
  int quad = lane >> 4, l15 = lane & 15;
  int n = nt*16 + l15;
  int u = n >> 2, g = n & 3;
  int row = g*512 + u;
  int kb = (kt & 15)*32 + quad*8;
  int s = kt >> 4;
  const float* src; int lo;
  if (mode == 0){ src = Whh; lo = (s==1); }
  else          { src = (s&1) ? Whh : Wih; lo = (s==2 || s==3); }
  short* op = Bp + (size_t)idx*8;
  #pragma unroll
  for (int j=0;j<8;j++){
    float v = src[(size_t)row*512 + kb + j];
    unsigned short hb = f2bf(v);
    op[j] = lo ? (short)f2bf(v - bf2f(hb)) : (short)hb;
  }
}

// ctx l0 B-pack: segs kt0..7 Whh hi; 8..15 Whh lo; 16..23 Whh hi (A=[hi|hi|lo])
__global__ void pack_ctx0(const float* __restrict__ Whh, short* __restrict__ Bp){
  int idx = blockIdx.x*blockDim.x + threadIdx.x;
  if (idx >= 2*24*64*64) return;
  int lane = idx & 63;
  int nt   = (idx >> 6) & 63;
  int r    = idx >> 12;
  int kt   = r % 24, dir = r / 24;
  int quad = lane >> 4, l15 = lane & 15;
  int n = nt*16 + l15;
  int u = n >> 2, g = n & 3;
  int row = g*256 + u;
  int lo = (kt >> 3) == 1;
  int k0 = (kt & 7)*32 + quad*8;
  const float* src = Whh + (size_t)dir*1024*256 + (size_t)row*256 + k0;
  short* op = Bp + (size_t)idx*8;
  #pragma unroll
  for (int j=0;j<8;j++){
    float v = src[j];
    unsigned short hb = f2bf(v);
    op[j] = lo ? (short)f2bf(v - bf2f(hb)) : (short)hb;
  }
}

// ctx l1 B-pack: kt 0..15 Wih hi | 16..23 Whh hi | 24..39 Wih lo | 40..47 Whh lo
// | 48..63 Wih hi | 64..71 Whh hi
__global__ void pack_ctx1(const float* __restrict__ Wih, const float* __restrict__ Whh,
                          short* __restrict__ Bp){
  int idx = blockIdx.x*blockDim.x + threadIdx.x;
  if (idx >= 2*72*64*64) return;
  int lane = idx & 63;
  int nt   = (idx >> 6) & 63;
  int r    = idx >> 12;
  int kt   = r % 72, dir = r / 72;
  int quad = lane >> 4, l15 = lane & 15;
  int n = nt*16 + l15;
  int u = n >> 2, g = n & 3;
  int row = g*256 + u;
  const float* W; int stride, k0, lo;
  if      (kt < 16){ W=Wih; stride=512; k0=kt*32;      lo=0; }
  else if (kt < 24){ W=Whh; stride=256; k0=(kt-16)*32; lo=0; }
  else if (kt < 40){ W=Wih; stride=512; k0=(kt-24)*32; lo=1; }
  else if (kt < 48){ W=Whh; stride=256; k0=(kt-40)*32; lo=1; }
  else if (kt < 64){ W=Wih; stride=512; k0=(kt-48)*32; lo=0; }
  else             { W=Whh; stride=256; k0=(kt-64)*32; lo=0; }
  const float* src = W + (size_t)dir*1024*stride + (size_t)row*stride + k0 + quad*8;
  short* op = Bp + (size_t)idx*8;
  #pragma unroll
  for (int j=0;j<8;j++){
    float v = src[j];
    unsigned short hb = f2bf(v);
    op[j] = lo ? (short)f2bf(v - bf2f(hb)) : (short)hb;
  }
}

// ctx layer-0 one step: grid (16,8,2), 256 thr; tile 64M x 128N.
__global__ void ctx0_step(const int* __restrict__ toks,
                          const float* __restrict__ ectx0p,
                          const short* __restrict__ Bp,
                          short* __restrict__ y0f, short* __restrict__ y0b,
                          float* __restrict__ cst, int s){
  const int dir = blockIdx.z;
  const int t = dir ? (L_SEQ-1-s) : s;
  short* y0 = dir ? y0b : y0f;
  const int m0 = blockIdx.x*64;
  const int ng = blockIdx.y;
  const int nb0 = ng*8, u0 = ng*32;
  const int w = threadIdx.x>>6, lane = threadIdx.x&63;
  const int quad = lane>>4, l15 = lane&15;
  f32x4 acc[8];
  #pragma unroll
  for (int i=0;i<8;i++) acc[i]=(f32x4){0.f,0.f,0.f,0.f};
  if (s > 0){
    const int tp = dir ? t+1 : t-1;
    const short* hp = y0 + (size_t)tp*BATCH*512;
    const size_t ar = (size_t)(m0 + w*16 + l15)*512;
    #pragma unroll
    for (int kt=0; kt<24; ++kt){
      const int off = ((kt>>3)==2) ? 256 : 0;   // A segs [hi|hi|lo]
      const short8 a = *(const short8*)(hp + ar + off + (kt&7)*32 + quad*8);
      const short* bb = Bp + (((size_t)(dir*24+kt)*64 + nb0)*64 + lane)*8;
      #pragma unroll
      for (int nt=0;nt<8;++nt){
        const short8 b = *(const short8*)(bb + (size_t)nt*512);
        acc[nt] = __builtin_amdgcn_mfma_f32_16x16x32_bf16(a,b,acc[nt],0,0,0);
      }
    }
  }
  __shared__ float zt[64][132];
  #pragma unroll
  for (int nt=0;nt<8;++nt)
    #pragma unroll
    for (int r=0;r<4;r++)
      zt[w*16+quad*4+r][nt*16+l15] = acc[nt][r];
  __syncthreads();
  for (int i=0;i<8;i++){
    int p = threadIdx.x + 256*i;
    int el = p>>5, ul = p&31;
    int e = m0 + el, u = u0 + ul;
    int tk = toks[e*L_SEQ + t];
    const float* ec = ectx0p + (size_t)(dir*5+tk)*1024 + u*4;
    float z0 = zt[el][ul*4+0] + ec[0];
    float z1 = zt[el][ul*4+1] + ec[1];
    float z2 = zt[el][ul*4+2] + ec[2];
    float z3 = zt[el][ul*4+3] + ec[3];
    float ig=sigf(z0), fg=sigf(z1), gg=tanhf(z2), og=sigf(z3);
    size_t ci = ((size_t)dir*BATCH + e)*256 + u;
    float cprev = (s==0) ? 0.f : cst[ci];
    float c = fg*cprev + ig*gg;
    float h = og*tanhf(c);
    cst[ci] = c;
    unsigned short hh = f2bf(h);
    unsigned short hl = f2bf(h - bf2f(hh));
    short* yr = y0 + ((size_t)t*BATCH + e)*512;
    yr[u] = (short)hh; yr[256+u] = (short)hl;
  }
}

// ctx layer-1 one step: x = [y0f[t]; y0b[t]], h1 ping-pong; finals at t==t_store.
__global__ void ctx1_step(const short* __restrict__ y0f, const short* __restrict__ y0b,
                          const short* __restrict__ h1in, short* __restrict__ h1out,
                          const short* __restrict__ Bp,
                          const float* __restrict__ bp1,
                          float* __restrict__ cst,
                          float* __restrict__ finals,
                          int s, int t_store){
  const int dir = blockIdx.z;
  const int t = dir ? (L_SEQ-1-s) : s;
  const int m0 = blockIdx.x*64;
  const int ng = blockIdx.y;
  const int nb0 = ng*8, u0 = ng*32;
  const int w = threadIdx.x>>6, lane = threadIdx.x&63;
  const int quad = lane>>4, l15 = lane&15;
  const size_t ar = (size_t)(m0 + w*16 + l15)*512;
  const short* xf = y0f + (size_t)t*BATCH*512;
  const short* xb = y0b + (size_t)t*BATCH*512;
  const short* hh = h1in + (size_t)dir*BATCH*512;
  f32x4 acc[8];
  #pragma unroll
  for (int i=0;i<8;i++) acc[i]=(f32x4){0.f,0.f,0.f,0.f};
  const bool hz = (s==0);
  auto seg = [&](const short* base, int off, int kt0, bool skip){
    if (skip) return;
    #pragma unroll
    for (int j=0;j<8;j++){
      const short8 a = *(const short8*)(base + ar + off + j*32 + quad*8);
      const short* bb = Bp + (((size_t)(dir*72 + kt0 + j)*64 + nb0)*64 + lane)*8;
      #pragma unroll
      for (int nt=0;nt<8;++nt){
        const short8 b = *(const short8*)(bb + (size_t)nt*512);
        acc[nt] = __builtin_amdgcn_mfma_f32_16x16x32_bf16(a,b,acc[nt],0,0,0);
      }
    }
  };
  seg(xf, 0,   0,  false);   // x_hi(f) . Wx_hi
  seg(xb, 0,   8,  false);   // x_hi(b) . Wx_hi
  seg(hh, 0,   16, hz);      // h_hi    . Wh_hi
  seg(xf, 0,   24, false);   // x_hi(f) . Wx_lo
  seg(xb, 0,   32, false);   // x_hi(b) . Wx_lo
  seg(hh, 0,   40, hz);      // h_hi    . Wh_lo
  seg(xf, 256, 48, false);   // x_lo(f) . Wx_hi
  seg(xb, 256, 56, false);   // x_lo(b) . Wx_hi
  seg(hh, 256, 64, hz);      // h_lo    . Wh_hi
  __shared__ float zt[64][132];
  #pragma unroll
  for (int nt=0;nt<8;++nt)
    #pragma unroll
    for (int r=0;r<4;r++)
      zt[w*16+quad*4+r][nt*16+l15] = acc[nt][r];
  __syncthreads();
  for (int i=0;i<8;i++){
    int p = threadIdx.x + 256*i;
    int el = p>>5, ul = p&31;
    int e = m0 + el, u = u0 + ul;
    const float* bb = bp1 + dir*1024 + u*4;
    float z0 = zt[el][ul*4+0] + bb[0];
    float z1 = zt[el][ul*4+1] + bb[1];
    float z2 = zt[el][ul*4+2] + bb[2];
    float z3 = zt[el][ul*4+3] + bb[3];
    float ig=sigf(z0), fg=sigf(z1), gg=tanhf(z2), og=sigf(z3);
    size_t ci = ((size_t)dir*BATCH + e)*256 + u;
    float cprev = (s==0) ? 0.f : cst[ci];
    float c = fg*cprev + ig*gg;
    float h = og*tanhf(c);
    cst[ci] = c;
    unsigned short hhv = f2bf(h);
    unsigned short hlv = f2bf(h - bf2f(hhv));
    short* hr = h1out + ((size_t)dir*BATCH + e)*512;
    hr[u] = (short)hhv; hr[256+u] = (short)hlv;
    if (t == t_store) finals[(size_t)e*512 + dir*256 + u] = h;
  }
}

// combined init: decoder h0/h1 packs (bf16 hi|lo), h1 fp32, c=0, tok=0
__global__ void combine_init(const float* __restrict__ lf, const float* __restrict__ rf,
                             short* __restrict__ h0p, short* __restrict__ h1p,
                             float* __restrict__ h1f,
                             float* __restrict__ c0, float* __restrict__ c1,
                             int* __restrict__ tok){
  int i = blockIdx.x*blockDim.x + threadIdx.x;
  if (i < BATCH*HG){
    float v = 0.5f*(lf[i]+rf[i]);
    int e = i >> 9, u = i & 511;
    unsigned short hh = f2bf(v);
    unsigned short hl = f2bf(v - bf2f(hh));
    h0p[(size_t)e*1024 + u]       = (short)hh;
    h0p[(size_t)e*1024 + 512 + u] = (short)hl;
    h1p[(size_t)e*1024 + u]       = (short)hh;
    h1p[(size_t)e*1024 + 512 + u] = (short)hl;
    h1f[i] = v;
    c0[i] = 0.f; c1[i] = 0.f;
  }
  if (i < BATCH) tok[i] = 0;
}

// ---------------- decoder (verified R2, unchanged) ----------------
__global__ void dec_l0(const int* __restrict__ tok,
                       const float* __restrict__ egen0p,
                       const short* __restrict__ Bp,
                       const short* __restrict__ hprev,
                       short* __restrict__ hnew,
                       float* __restrict__ cst){
  const int m0 = blockIdx.x * 64;
  const int nb0 = blockIdx.y * 8;
  const int u0 = blockIdx.y * 32;
  const int w = threadIdx.x >> 6;
  const int lane = threadIdx.x & 63;
  const int quad = lane >> 4, l15 = lane & 15;
  f32x4 acc[8];
  #pragma unroll
  for (int i=0;i<8;i++) acc[i] = (f32x4){0.f,0.f,0.f,0.f};
  const size_t arow = (size_t)(m0 + w*16 + l15)*1024;
  for (int kt=0; kt<48; ++kt){
    const int s = kt >> 4;
    const int off = (s==2) ? 512 : 0;
    const short8 a = *(const short8*)(hprev + arow + off + (kt&15)*32 + quad*8);
    const short* bb = Bp + (((size_t)kt*128 + nb0)*64 + lane)*8;
    #pragma unroll
    for (int nt=0; nt<8; ++nt){
      const short8 b = *(const short8*)(bb + (size_t)nt*512);
      acc[nt] = __builtin_amdgcn_mfma_f32_16x16x32_bf16(a, b, acc[nt], 0, 0, 0);
    }
  }
  __shared__ float zt[64][132];
  #pragma unroll
  for (int nt=0; nt<8; ++nt)
    #pragma unroll
    for (int r=0;r<4;r++)
      zt[w*16 + quad*4 + r][nt*16 + l15] = acc[nt][r];
  __syncthreads();
  for (int i=0;i<8;i++){
    int p = threadIdx.x + 256*i;
    int el = p >> 5, ul = p & 31;
    int e = m0 + el, u = u0 + ul;
    const float* eg = egen0p + (size_t)tok[e]*2048 + (size_t)(u0+ul)*4;
    float z0 = zt[el][ul*4+0] + eg[0];
    float z1 = zt[el][ul*4+1] + eg[1];
    float z2 = zt[el][ul*4+2] + eg[2];
    float z3 = zt[el][ul*4+3] + eg[3];
    float ig = sigf(z0), fg = sigf(z1), gg = tanhf(z2), og = sigf(z3);
    size_t ci = (size_t)e*512 + u;
    float c = fg*cst[ci] + ig*gg;
    float h = og*tanhf(c);
    cst[ci] = c;
    unsigned short hh = f2bf(h);
    unsigned short hl = f2bf(h - bf2f(hh));
    hnew[(size_t)e*1024 + u]       = (short)hh;
    hnew[(size_t)e*1024 + 512 + u] = (short)hl;
  }
}

__global__ void dec_l1(const short* __restrict__ h0new,
                       const short* __restrict__ h1prev,
                       const short* __restrict__ Bp,
                       const float* __restrict__ b1p,
                       short* __restrict__ h1new,
                       float* __restrict__ h1f,
                       float* __restrict__ cst){
  const int m0 = blockIdx.x * 64;
  const int nb0 = blockIdx.y * 8;
  const int u0 = blockIdx.y * 32;
  const int w = threadIdx.x >> 6;
  const int lane = threadIdx.x & 63;
  const int quad = lane >> 4, l15 = lane & 15;
  f32x4 acc[8];
  #pragma unroll
  for (int i=0;i<8;i++) acc[i] = (f32x4){0.f,0.f,0.f,0.f};
  const size_t arow = (size_t)(m0 + w*16 + l15)*1024;
  for (int kt=0; kt<96; ++kt){
    const int s = kt >> 4;
    const short* abuf = (s & 1) ? h1prev : h0new;
    const int off = (s >= 4) ? 512 : 0;
    const short8 a = *(const short8*)(abuf + arow + off + (kt&15)*32 + quad*8);
    const short* bb = Bp + (((size_t)kt*128 + nb0)*64 + lane)*8;
    #pragma unroll
    for (int nt=0; nt<8; ++nt){
      const short8 b = *(const short8*)(bb + (size_t)nt*512);
      acc[nt] = __builtin_amdgcn_mfma_f32_16x16x32_bf16(a, b, acc[nt], 0, 0, 0);
    }
  }
  __shared__ float zt[64][132];
  #pragma unroll
  for (int nt=0; nt<8; ++nt)
    #pragma unroll
    for (int r=0;r<4;r++)
      zt[w*16 + quad*4 + r][nt*16 + l15] = acc[nt][r];
  __syncthreads();
  for (int i=0;i<8;i++){
    int p = threadIdx.x + 256*i;
    int el = p >> 5, ul = p & 31;
    int e = m0 + el, u = u0 + ul;
    const float* bp = b1p + (size_t)(u0+ul)*4;
    float z0 = zt[el][ul*4+0] + bp[0];
    float z1 = zt[el][ul*4+1] + bp[1];
    float z2 = zt[el][ul*4+2] + bp[2];
    float z3 = zt[el][ul*4+3] + bp[3];
    float ig = sigf(z0), fg = sigf(z1), gg = tanhf(z2), og = sigf(z3);
    size_t ci = (size_t)e*512 + u;
    float c = fg*cst[ci] + ig*gg;
    float h = og*tanhf(c);
    cst[ci] = c;
    unsigned short hh = f2bf(h);
    unsigned short hl = f2bf(h - bf2f(hh));
    h1new[(size_t)e*1024 + u]       = (short)hh;
    h1new[(size_t)e*1024 + 512 + u] = (short)hl;
    h1f[ci] = h;
  }
}

__global__ void dec_out(const float* __restrict__ h1,
                        const float* __restrict__ outW,
                        const float* __restrict__ outb,
                        float* __restrict__ out,
                        int* __restrict__ tok, int t){
  const int lane = threadIdx.x & 63;
  const int e = blockIdx.x*4 + (threadIdx.x >> 6);
  const float* h = h1 + (size_t)e*512;
  float s0=0,s1=0,s2=0,s3=0,s4=0;
  for (int k=lane;k<512;k+=64){
    float hv = h[k];
    s0 += hv*outW[k];
    s1 += hv*outW[512+k];
    s2 += hv*outW[1024+k];
    s3 += hv*outW[1536+k];
    s4 += hv*outW[2048+k];
  }
  #pragma unroll
  for (int off=32; off>0; off>>=1){
    s0 += __shfl_down(s0, off);
    s1 += __shfl_down(s1, off);
    s2 += __shfl_down(s2, off);
    s3 += __shfl_down(s3, off);
    s4 += __shfl_down(s4, off);
  }
  if (lane==0){
    float l[5] = { s0+outb[0], s1+outb[1], s2+outb[2], s3+outb[3], s4+outb[4] };
    float* op = out + ((size_t)e*TDEC + t)*5;
    float best = l[0]; int bi = 0;
    op[0] = l[0];
    #pragma unroll
    for (int v=1;v<5;v++){
      op[v] = l[v];
      if (l[v] > best){ best = l[v]; bi = v; }
    }
    tok[e] = bi;
  }
}

extern "C" void kernel_launch(void* const* d_in, const int* in_sizes, int n_in,
                              void* d_out, int out_size, void* d_ws, size_t ws_size,
                              hipStream_t stream){
  (void)in_sizes; (void)n_in; (void)out_size;
  const int*   leftc    = (const int*)d_in[0];
  const int*   rightc   = (const int*)d_in[1];
  const float* emb      = (const float*)d_in[3];
  const float* ctx0_Wih = (const float*)d_in[4];
  const float* ctx0_Whh = (const float*)d_in[5];
  const float* ctx0_b   = (const float*)d_in[6];
  const float* ctx1_Wih = (const float*)d_in[7];
  const float* ctx1_Whh = (const float*)d_in[8];
  const float* ctx1_b   = (const float*)d_in[9];
  const float* gen0_Wih = (const float*)d_in[10];
  const float* gen0_Whh = (const float*)d_in[11];
  const float* gen0_b   = (const float*)d_in[12];
  const float* gen1_Wih = (const float*)d_in[13];
  const float* gen1_Whh = (const float*)d_in[14];
  const float* gen1_b   = (const float*)d_in[15];
  const float* out_W    = (const float*)d_in[16];
  const float* out_b    = (const float*)d_in[17];
  float* out = (float*)d_out;

  char* p = (char*)d_ws;
  auto carveB = [&](size_t nbytes)->char*{
    char* r = p;
    p += ((nbytes + 255) & ~(size_t)255);
    return r;
  };
  // ---- Union U (20 MiB): ctx-only {BpC0,BpC1,h1cA,h1cB,cstC0,cstC1}
  //      overlaid with decoder packs {BpD0,BpD1} (written after ctx).
  char*  U      = carveB((size_t)20*1024*1024);
  short* BpC0   = (short*)U;                                   // 3 MiB
  short* BpC1   = (short*)(U + (size_t)3*1024*1024);           // 9 MiB
  short* h1cA   = (short*)(U + (size_t)12*1024*1024);          // 2 MiB
  short* h1cB   = (short*)(U + (size_t)14*1024*1024);          // 2 MiB
  float* cstC0  = (float*)(U + (size_t)16*1024*1024);          // 2 MiB
  float* cstC1  = (float*)(U + (size_t)18*1024*1024);          // 2 MiB
  short* BpD0   = (short*)U;                                   // 6 MiB (after ctx)
  short* BpD1   = (short*)(U + (size_t)6*1024*1024);           // 12 MiB (after ctx)
  // ---- persistent smalls
  float* ectx0p = (float*)carveB(2*5*1024*4);
  float* egen0p = (float*)carveB(5*2048*4);
  float* b1p    = (float*)carveB(2048*4);
  float* ctxb1p = (float*)carveB(2048*4);
  float* leftF  = (float*)carveB((size_t)BATCH*HG*4);
  float* rightF = (float*)carveB((size_t)BATCH*HG*4);
  int*   tok    = (int*)carveB(BATCH*4);
  // ---- Union Y (200 MiB): {y0f,y0b} overlaid with decoder state
  //      (combine_init writes after last ctx1_step read).
  char*  Y      = carveB((size_t)200*1024*1024);
  short* y0f    = (short*)Y;                                   // 100 MiB
  short* y0b    = (short*)(Y + (size_t)100*1024*1024);         // 100 MiB
  short* h0pA   = (short*)Y;                                   // 2 MiB each
  short* h0pB   = (short*)(Y + (size_t)2*1024*1024);
  short* h1pA   = (short*)(Y + (size_t)4*1024*1024);
  short* h1pB   = (short*)(Y + (size_t)6*1024*1024);
  float* h1f32  = (float*)(Y + (size_t)8*1024*1024);
  float* c0s    = (float*)(Y + (size_t)10*1024*1024);
  float* c1s    = (float*)(Y + (size_t)12*1024*1024);
  if ((size_t)(p - (char*)d_ws) > ws_size) return;  // ~224.2 MiB total

  embprep<<<(24576+255)/256, 256, 0, stream>>>(emb, ctx0_Wih, ctx0_b,
                                               gen0_Wih, gen0_b, gen1_b, ctx1_b,
                                               ectx0p, egen0p, b1p, ctxb1p);
  pack_ctx0<<<(2*24*64*64+255)/256, 256, 0, stream>>>(ctx0_Whh, BpC0);
  pack_ctx1<<<(2*72*64*64+255)/256, 256, 0, stream>>>(ctx1_Wih, ctx1_Whh, BpC1);

  for (int side=0; side<2; ++side){
    const int* toks = side ? rightc : leftc;
    float* fin = side ? rightF : leftF;
    int tst = side ? 0 : (L_SEQ-1);
    for (int s=0;s<L_SEQ;s++)
      ctx0_step<<<dim3(16,8,2), 256, 0, stream>>>(toks, ectx0p, BpC0,
                                                  y0f, y0b, cstC0, s);
    for (int s=0;s<L_SEQ;s++){
      short* hin  = (s&1) ? h1cB : h1cA;
      short* hout = (s&1) ? h1cA : h1cB;
      ctx1_step<<<dim3(16,8,2), 256, 0, stream>>>(y0f, y0b, hin, hout, BpC1,
                                                  ctxb1p, cstC1, fin, s, tst);
    }
  }

  // decoder packs AFTER ctx (they overwrite the ctx region of union U)
  pack_b<<<(48*128*64+255)/256, 256, 0, stream>>>(gen0_Whh, gen0_Whh, BpD0, 48, 0);
  pack_b<<<(96*128*64+255)/256, 256, 0, stream>>>(gen1_Wih, gen1_Whh, BpD1, 96, 1);

  combine_init<<<(BATCH*HG+255)/256, 256, 0, stream>>>(leftF, rightF,
                                                       h0pA, h1pA, h1f32,
                                                       c0s, c1s, tok);

  for (int t=0;t<TDEC;t++){
    short* h0in  = (t&1) ? h0pB : h0pA;
    short* h0out = (t&1) ? h0pA : h0pB;
    short* h1in  = (t&1) ? h1pB : h1pA;
    short* h1out = (t&1) ? h1pA : h1pB;
    dec_l0<<<dim3(16,16), 256, 0, stream>>>(tok, egen0p, BpD0, h0in, h0out, c0s);
    dec_l1<<<dim3(16,16), 256, 0, stream>>>(h0out, h1in, BpD1, b1p,
                                            h1out, h1f32, c1s);
    dec_out<<<256, 256, 0, stream>>>(h1f32, out_W, out_b, out, tok, t);
  }
}